// Round 3
// baseline (842.420 us; speedup 1.0000x reference)
//
#include <hip/hip_runtime.h>
#include <cstdint>
#include <cstddef>

#define D_MODEL 768
#define NBATCH 8
#define SEQLEN 2048
#define NROWS (NBATCH*SEQLEN)   // 16384

typedef __attribute__((ext_vector_type(4))) float  f32x4;
typedef __attribute__((ext_vector_type(8))) __bf16 bf16x8;
typedef __attribute__((ext_vector_type(4))) __bf16 bf16x4;

#define MFMA16(a,b,c) __builtin_amdgcn_mfma_f32_16x16x32_bf16(a,b,c,0,0,0)

// ---------------- workspace layout (bytes) ----------------
static constexpr size_t SZ_ACT_BF16 = (size_t)NROWS * D_MODEL * 2;  // 25165824
static constexpr size_t OFF_H1 = 0;
static constexpr size_t OFF_Q  = OFF_H1 + SZ_ACT_BF16;
static constexpr size_t OFF_K  = OFF_Q  + SZ_ACT_BF16;
static constexpr size_t OFF_V  = OFF_K  + SZ_ACT_BF16;   // Q,K,V contiguous (fused QKV GEMM relies on this)
static constexpr size_t OFF_VT = OFF_V  + SZ_ACT_BF16;
static constexpr size_t OFF_X2 = OFF_VT + SZ_ACT_BF16;              // fp32 buffer
static constexpr size_t OFF_W  = OFF_X2 + (size_t)NROWS * D_MODEL * 4;

__device__ __forceinline__ float gelu_exact(float x) {
  return 0.5f * x * (1.0f + erff(x * 0.70710678118654752f));
}

// ---------------- weight fp32 -> bf16 ----------------
__global__ __launch_bounds__(256) void k_cvt5(
    const float* __restrict__ s0, const float* __restrict__ s1,
    const float* __restrict__ s2, const float* __restrict__ s3,
    const float* __restrict__ s4, __bf16* __restrict__ dst)
{
  const int wsel = blockIdx.y;
  const float* s = wsel==0 ? s0 : wsel==1 ? s1 : wsel==2 ? s2 : wsel==3 ? s3 : s4;
  const size_t i = ((size_t)blockIdx.x*256 + threadIdx.x)*4;
  float4 v = *(const float4*)(s + i);
  bf16x4 o;
  o[0] = (__bf16)v.x; o[1] = (__bf16)v.y; o[2] = (__bf16)v.z; o[3] = (__bf16)v.w;
  *(bf16x4*)(dst + (size_t)wsel*589824 + i) = o;
}

// ---------------- LayerNorm (wave per row) ----------------
__global__ __launch_bounds__(256) void k_layernorm(
    const float* __restrict__ x, const float* __restrict__ g,
    const float* __restrict__ be, __bf16* __restrict__ out)
{
  const int row  = blockIdx.x*4 + (threadIdx.x>>6);
  const int lane = threadIdx.x & 63;
  const float4* xr = (const float4*)(x + (size_t)row*D_MODEL);
  float4 v[3];
  float s = 0.f, ss = 0.f;
#pragma unroll
  for (int j=0;j<3;j++){
    v[j] = xr[lane + 64*j];
    s  += v[j].x + v[j].y + v[j].z + v[j].w;
    ss += v[j].x*v[j].x + v[j].y*v[j].y + v[j].z*v[j].z + v[j].w*v[j].w;
  }
#pragma unroll
  for (int d=1; d<64; d<<=1){ s += __shfl_xor(s,d); ss += __shfl_xor(ss,d); }
  const float mu   = s  * (1.f/768.f);
  const float var  = ss * (1.f/768.f) - mu*mu;
  const float rstd = rsqrtf(var + 1e-5f);
  __bf16* orow = out + (size_t)row*D_MODEL;
#pragma unroll
  for (int j=0;j<3;j++){
    const int c0 = (lane + 64*j)*4;
    bf16x4 o;
    o[0] = (__bf16)((v[j].x - mu)*rstd*g[c0+0] + be[c0+0]);
    o[1] = (__bf16)((v[j].y - mu)*rstd*g[c0+1] + be[c0+1]);
    o[2] = (__bf16)((v[j].z - mu)*rstd*g[c0+2] + be[c0+2]);
    o[3] = (__bf16)((v[j].w - mu)*rstd*g[c0+3] + be[c0+3]);
    *(bf16x4*)(orow + c0) = o;
  }
}

// ---------------- generic NT GEMM body ----------------
// C[M,768] = A[M,768] @ B[768,768]^T + bias ; EPI: 1 = bf16+GELU, 2 = f32+GELU+resid
template<int EPI>
__global__ __launch_bounds__(256) void k_gemm_nt(
    const __bf16* __restrict__ A, const __bf16* __restrict__ B,
    const float* __restrict__ bias, const float* __restrict__ resid,
    void* __restrict__ Cout)
{
  __shared__ __bf16 As[128*64];
  __shared__ __bf16 Bs[128*64];
  const int tid = threadIdx.x;
  const int w = tid>>6, lane = tid&63;
  const int l16 = lane&15, l4 = lane>>4;
  const int bm = blockIdx.x / 6, bn = blockIdx.x % 6;
  const int wr = w>>1, wc = w&1;
  const int srow = lane>>3, schunk = lane&7;
  f32x4 acc[4][4] = {};

  const __bf16* Ab = A + (size_t)bm*128*D_MODEL;
  const __bf16* Bb = B + (size_t)bn*128*D_MODEL;

  for (int k0=0; k0<D_MODEL; k0+=64){
#pragma unroll
    for (int i=0;i<4;i++){
      const int row = i*32 + w*8 + srow;
      __builtin_amdgcn_global_load_lds(
        (const __attribute__((address_space(1))) void*)(Ab + (size_t)row*D_MODEL + k0 + schunk*8),
        (__attribute__((address_space(3))) void*)(As + i*2048 + w*512), 16, 0, 0);
      __builtin_amdgcn_global_load_lds(
        (const __attribute__((address_space(1))) void*)(Bb + (size_t)row*D_MODEL + k0 + schunk*8),
        (__attribute__((address_space(3))) void*)(Bs + i*2048 + w*512), 16, 0, 0);
    }
    __syncthreads();
#pragma unroll
    for (int kk=0;kk<2;kk++){
      bf16x8 af[4], bfr[4];
#pragma unroll
      for (int m=0;m<4;m++)
        af[m] = *(const bf16x8*)(As + (wr*64 + m*16 + l16)*64 + kk*32 + l4*8);
#pragma unroll
      for (int n=0;n<4;n++)
        bfr[n] = *(const bf16x8*)(Bs + (wc*64 + n*16 + l16)*64 + kk*32 + l4*8);
#pragma unroll
      for (int m=0;m<4;m++)
#pragma unroll
        for (int n=0;n<4;n++)
          acc[m][n] = MFMA16(af[m], bfr[n], acc[m][n]);
    }
    __syncthreads();
  }

  const int row0 = bm*128 + wr*64, col0 = bn*128 + wc*64;
#pragma unroll
  for (int n=0;n<4;n++){
    const int col = col0 + n*16 + l16;
    const float bv = bias[col];
#pragma unroll
    for (int m=0;m<4;m++){
#pragma unroll
      for (int r=0;r<4;r++){
        const int row = row0 + m*16 + l4*4 + r;
        float v = acc[m][n][r] + bv;
        if (EPI >= 1) v = gelu_exact(v);
        if (EPI == 2) {
          v += resid[(size_t)row*D_MODEL + col];
          ((float*)Cout)[(size_t)row*D_MODEL + col] = v;
        } else {
          ((__bf16*)Cout)[(size_t)row*D_MODEL + col] = (__bf16)v;
        }
      }
    }
  }
}

// ---------------- fused QKV GEMM: N = 3*768, weights/outs contiguous ----------------
__global__ __launch_bounds__(256) void k_gemm_qkv(
    const __bf16* __restrict__ A, const __bf16* __restrict__ Wcat,
    const float* __restrict__ bq, const float* __restrict__ bk,
    const float* __restrict__ bv, __bf16* __restrict__ out)
{
  __shared__ __bf16 As[128*64];
  __shared__ __bf16 Bs[128*64];
  const int tid = threadIdx.x;
  const int w = tid>>6, lane = tid&63;
  const int l16 = lane&15, l4 = lane>>4;
  const int bm = blockIdx.x / 18, bn = blockIdx.x % 18;
  const int seg = bn/6, bn2 = bn%6;
  const float* bias = seg==0 ? bq : seg==1 ? bk : bv;
  const __bf16* Bb = Wcat + (size_t)seg*589824 + (size_t)bn2*128*D_MODEL;
  __bf16* C = out + (size_t)seg*((size_t)NROWS*D_MODEL);
  const int wr = w>>1, wc = w&1;
  const int srow = lane>>3, schunk = lane&7;
  f32x4 acc[4][4] = {};
  const __bf16* Ab = A + (size_t)bm*128*D_MODEL;

  for (int k0=0; k0<D_MODEL; k0+=64){
#pragma unroll
    for (int i=0;i<4;i++){
      const int row = i*32 + w*8 + srow;
      __builtin_amdgcn_global_load_lds(
        (const __attribute__((address_space(1))) void*)(Ab + (size_t)row*D_MODEL + k0 + schunk*8),
        (__attribute__((address_space(3))) void*)(As + i*2048 + w*512), 16, 0, 0);
      __builtin_amdgcn_global_load_lds(
        (const __attribute__((address_space(1))) void*)(Bb + (size_t)row*D_MODEL + k0 + schunk*8),
        (__attribute__((address_space(3))) void*)(Bs + i*2048 + w*512), 16, 0, 0);
    }
    __syncthreads();
#pragma unroll
    for (int kk=0;kk<2;kk++){
      bf16x8 af[4], bfr[4];
#pragma unroll
      for (int m=0;m<4;m++)
        af[m] = *(const bf16x8*)(As + (wr*64 + m*16 + l16)*64 + kk*32 + l4*8);
#pragma unroll
      for (int n=0;n<4;n++)
        bfr[n] = *(const bf16x8*)(Bs + (wc*64 + n*16 + l16)*64 + kk*32 + l4*8);
#pragma unroll
      for (int m=0;m<4;m++)
#pragma unroll
        for (int n=0;n<4;n++)
          acc[m][n] = MFMA16(af[m], bfr[n], acc[m][n]);
    }
    __syncthreads();
  }

  const int row0 = bm*128 + wr*64, col0 = bn2*128 + wc*64;
#pragma unroll
  for (int n=0;n<4;n++){
    const int col = col0 + n*16 + l16;
    const float bvv = bias[col];
#pragma unroll
    for (int m=0;m<4;m++){
#pragma unroll
      for (int r=0;r<4;r++){
        const int row = row0 + m*16 + l4*4 + r;
        C[(size_t)row*D_MODEL + col] = (__bf16)(acc[m][n][r] + bvv);
      }
    }
  }
}

// ---------------- V transpose: v[b,t,d] -> vT[b,d,t] ----------------
__global__ __launch_bounds__(256) void k_transpose_v(
    const __bf16* __restrict__ v, __bf16* __restrict__ vT)
{
  __shared__ __bf16 tile[64][72];
  const int b = blockIdx.z;
  const int t0 = blockIdx.x*64, d0 = blockIdx.y*64;
  const int tid = threadIdx.x;
  const int rr = (tid>>3)*2, cc = (tid&7)*8;
  const __bf16* src = v + ((size_t)b*SEQLEN + t0)*D_MODEL + d0;
#pragma unroll
  for (int j=0;j<2;j++){
    bf16x8 val = *(const bf16x8*)(src + (size_t)(rr+j)*D_MODEL + cc);
#pragma unroll
    for (int e=0;e<8;e++) tile[cc+e][rr+j] = val[e];
  }
  __syncthreads();
  __bf16* dst = vT + ((size_t)b*D_MODEL + d0)*SEQLEN + t0;
#pragma unroll
  for (int j=0;j<2;j++){
    bf16x8 o;
#pragma unroll
    for (int e=0;e<8;e++) o[e] = tile[rr+j][cc+e];
    *(bf16x8*)(dst + (size_t)(rr+j)*SEQLEN + cc) = o;
  }
}

// ---------------- flash attention v3 + residual ----------------
// 8 waves, QBLK=32 q-rows, KV tile 256, full D=768, no register spill:
// per-lane state: o[2][6] (48) + s[2][2] (16) + m/l (16 scalar) ~= 120 VGPR peak.
// QK^T: wave w computes S[0..32][w*32..+32] full-depth (no cross-wave reduce of scores).
// PV: wave w owns O cols [w*96, w*96+96). 3 barriers per 256-tile.
// LDS 66 KB -> 2 blocks/CU (16 waves/CU) for latency hiding.
#define QBLK 32
#define TBLK 256
__global__ __launch_bounds__(512,4) void k_flash3(
    const __bf16* __restrict__ q, const __bf16* __restrict__ k,
    const __bf16* __restrict__ vT, const float* __restrict__ x,
    float* __restrict__ x2)
{
  __shared__ __bf16 Qs[QBLK*768];       // 48 KB, XOR-swizzled 16B chunks
  __shared__ __bf16 Ps[QBLK*TBLK];      // 16 KB, XOR-swizzled
  __shared__ float pmax[8][QBLK];
  __shared__ float psum[8][QBLK];

  const int tid = threadIdx.x, w = tid>>6, lane = tid&63;
  const int l16 = lane&15, l4 = lane>>4;
  const int b = blockIdx.x & 7, qt = blockIdx.x >> 3;   // batch->XCD affinity
  const __bf16* qg = q  + ((size_t)b*SEQLEN + qt*QBLK)*D_MODEL;
  const __bf16* kg = k  + (size_t)b*SEQLEN*D_MODEL;
  const __bf16* vg = vT + (size_t)b*D_MODEL*SEQLEN;
  const float scale = 0.03608439182435161f;  // 1/sqrt(768)

  // stage Q -> LDS (swizzled): 3072 chunks of 16B, 6 per thread
#pragma unroll
  for (int j=0;j<6;j++){
    const int id = tid + 512*j;
    const int row = id/96, c = id%96;
    bf16x8 v = *(const bf16x8*)(qg + (size_t)row*D_MODEL + c*8);
    *(bf16x8*)(Qs + row*768 + ((c ^ (row&7))*8)) = v;
  }
  __syncthreads();

  f32x4 o[2][6] = {};
  f32x4 m_run[2], l_run[2];
#pragma unroll
  for (int m=0;m<2;m++)
#pragma unroll
    for (int r=0;r<4;r++){ m_run[m][r] = -1e30f; l_run[m][r] = 0.f; }

  for (int t0=0; t0<SEQLEN; t0+=TBLK){
    // ---- QK^T (full 768-deep): S[32][w*32..+32] ----
    f32x4 s[2][2] = {};
    __builtin_amdgcn_s_setprio(1);
#pragma unroll 4
    for (int kk=0; kk<24; kk++){
      const int qswz = ((kk*4 + l4) ^ (l16&7))*8;
      const bf16x8 a0 = *(const bf16x8*)(Qs + (     l16)*768 + qswz);
      const bf16x8 a1 = *(const bf16x8*)(Qs + (16 + l16)*768 + qswz);
      const bf16x8 kf0 = *(const bf16x8*)(kg + (size_t)(t0 + w*32 +      l16)*D_MODEL + kk*32 + l4*8);
      const bf16x8 kf1 = *(const bf16x8*)(kg + (size_t)(t0 + w*32 + 16 + l16)*D_MODEL + kk*32 + l4*8);
      s[0][0] = MFMA16(a0, kf0, s[0][0]);
      s[1][0] = MFMA16(a1, kf0, s[1][0]);
      s[0][1] = MFMA16(a0, kf1, s[0][1]);
      s[1][1] = MFMA16(a1, kf1, s[1][1]);
    }
    __builtin_amdgcn_s_setprio(0);

    // scale + per-wave rowmax over its 32 cols
#pragma unroll
    for (int m=0;m<2;m++)
#pragma unroll
      for (int n=0;n<2;n++)
#pragma unroll
        for (int r=0;r<4;r++) s[m][n][r] *= scale;
#pragma unroll
    for (int m=0;m<2;m++)
#pragma unroll
      for (int r=0;r<4;r++){
        float v = fmaxf(s[m][0][r], s[m][1][r]);
#pragma unroll
        for (int d=1; d<16; d<<=1) v = fmaxf(v, __shfl_xor(v, d));
        if (l16==0) pmax[w][m*16 + l4*4 + r] = v;
      }
    __syncthreads();   // b1: pmax ready

    // ---- m_new (vector form, rows = m*16 + l4*4 + 0..3) ----
    f32x4 mnew[2];
#pragma unroll
    for (int m=0;m<2;m++){
      f32x4 mv = *(const f32x4*)&pmax[0][m*16 + l4*4];
#pragma unroll
      for (int ww=1; ww<8; ww++){
        const f32x4 t = *(const f32x4*)&pmax[ww][m*16 + l4*4];
#pragma unroll
        for (int r=0;r<4;r++) mv[r] = fmaxf(mv[r], t[r]);
      }
#pragma unroll
      for (int r=0;r<4;r++) mnew[m][r] = fmaxf(m_run[m][r], mv[r]);
    }

    // ---- exp, partial row-sums, write P (bf16, swizzled) ----
#pragma unroll
    for (int m=0;m<2;m++)
#pragma unroll
      for (int r=0;r<4;r++){
        const float mn = mnew[m][r];
        float sum = 0.f;
#pragma unroll
        for (int n=0;n<2;n++){
          const float e = __expf(s[m][n][r] - mn);
          s[m][n][r] = e; sum += e;
        }
#pragma unroll
        for (int d=1; d<16; d<<=1) sum += __shfl_xor(sum, d);
        const int row = m*16 + l4*4 + r;
        if (l16==0) psum[w][row] = sum;
#pragma unroll
        for (int n=0;n<2;n++){
          const int col = w*32 + n*16 + l16;
          Ps[row*TBLK + (((col>>3) ^ (row&7))<<3) + (col&7)] = (__bf16)s[m][n][r];
        }
      }
    __syncthreads();   // b2: P + psum ready

    // ---- alpha, l_run, rescale O ----
#pragma unroll
    for (int m=0;m<2;m++){
      f32x4 sm = *(const f32x4*)&psum[0][m*16 + l4*4];
#pragma unroll
      for (int ww=1; ww<8; ww++){
        const f32x4 t = *(const f32x4*)&psum[ww][m*16 + l4*4];
#pragma unroll
        for (int r=0;r<4;r++) sm[r] += t[r];
      }
      f32x4 al;
#pragma unroll
      for (int r=0;r<4;r++){
        al[r] = __expf(m_run[m][r] - mnew[m][r]);
        l_run[m][r] = l_run[m][r]*al[r] + sm[r];
        m_run[m][r] = mnew[m][r];
      }
#pragma unroll
      for (int n=0;n<6;n++) o[m][n] *= al;
    }

    // ---- PV: O[32 x 96cols] += P[32 x 256] @ V' ----
    __builtin_amdgcn_s_setprio(1);
#pragma unroll 2
    for (int ks=0; ks<8; ks++){
      const bf16x8 pf0 = *(const bf16x8*)(Ps + (     l16)*TBLK + (((ks*4 + l4) ^ (l16&7))<<3));
      const bf16x8 pf1 = *(const bf16x8*)(Ps + (16 + l16)*TBLK + (((ks*4 + l4) ^ (l16&7))<<3));
#pragma unroll
      for (int n=0;n<6;n++){
        const bf16x8 vf = *(const bf16x8*)(vg + (size_t)(w*96 + n*16 + l16)*SEQLEN + t0 + ks*32 + l4*8);
        o[0][n] = MFMA16(pf0, vf, o[0][n]);
        o[1][n] = MFMA16(pf1, vf, o[1][n]);
      }
    }
    __builtin_amdgcn_s_setprio(0);
    __syncthreads();   // b3: Ps/pmax/psum consumed
  }

  // ---- epilogue: /l, + residual, store fp32 ----
  const float* xr = x  + ((size_t)b*SEQLEN + qt*QBLK)*D_MODEL;
  float*       ob = x2 + ((size_t)b*SEQLEN + qt*QBLK)*D_MODEL;
#pragma unroll
  for (int m=0;m<2;m++){
    f32x4 inv;
#pragma unroll
    for (int r=0;r<4;r++) inv[r] = 1.f / l_run[m][r];
#pragma unroll
    for (int r=0;r<4;r++){
      const int row = m*16 + l4*4 + r;
#pragma unroll
      for (int n=0;n<6;n++){
        const int col = w*96 + n*16 + l16;
        ob[(size_t)row*D_MODEL + col] = o[m][n][r]*inv[r] + xr[(size_t)row*D_MODEL + col];
      }
    }
  }
}

// ---------------- launch ----------------
extern "C" void kernel_launch(void* const* d_in, const int* in_sizes, int n_in,
                              void* d_out, int out_size, void* d_ws, size_t ws_size,
                              hipStream_t stream)
{
  const float* x   = (const float*)d_in[0];
  const float* Wq  = (const float*)d_in[1];
  const float* bq  = (const float*)d_in[2];
  const float* Wk  = (const float*)d_in[3];
  const float* bk  = (const float*)d_in[4];
  const float* Wv  = (const float*)d_in[5];
  const float* bv  = (const float*)d_in[6];
  const float* W1  = (const float*)d_in[7];
  const float* b1  = (const float*)d_in[8];
  const float* W2  = (const float*)d_in[9];
  const float* b2  = (const float*)d_in[10];
  const float* g1  = (const float*)d_in[11];
  const float* be1 = (const float*)d_in[12];
  const float* g2  = (const float*)d_in[13];
  const float* be2 = (const float*)d_in[14];
  (void)in_sizes; (void)n_in; (void)out_size; (void)ws_size;

  char* ws = (char*)d_ws;
  __bf16* h1  = (__bf16*)(ws + OFF_H1);
  __bf16* qb  = (__bf16*)(ws + OFF_Q);
  __bf16* vb  = (__bf16*)(ws + OFF_V);
  __bf16* vT  = (__bf16*)(ws + OFF_VT);
  float*  x2  = (float*)(ws + OFF_X2);
  __bf16* wbf = (__bf16*)(ws + OFF_W);
  __bf16* kb  = (__bf16*)(ws + OFF_K);
  __bf16* h2  = h1;   // reuse (h1 dead after QKV GEMM)
  __bf16* h3  = qb;   // reuse (q dead after attention)

  k_cvt5<<<dim3(576,5,1),256,0,stream>>>(Wq,Wk,Wv,W1,W2,wbf);
  k_layernorm<<<dim3(4096),256,0,stream>>>(x, g1, be1, h1);
  k_gemm_qkv<<<dim3(2304),256,0,stream>>>(h1, wbf, bq, bk, bv, qb);
  k_transpose_v<<<dim3(32,12,8),256,0,stream>>>(vb, vT);
  k_flash3<<<dim3(512),512,0,stream>>>(qb, kb, vT, x, x2);
  k_layernorm<<<dim3(4096),256,0,stream>>>(x2, g2, be2, h2);
  k_gemm_nt<1><<<dim3(768),256,0,stream>>>(h2, wbf + 3*589824, b1, nullptr, h3);
  k_gemm_nt<2><<<dim3(768),256,0,stream>>>(h3, wbf + 4*589824, b2, x2, d_out);
}

// Round 4
// 683.495 us; speedup vs baseline: 1.2325x; 1.2325x over previous
//
#include <hip/hip_runtime.h>
#include <cstdint>
#include <cstddef>

#define D_MODEL 768
#define NBATCH 8
#define SEQLEN 2048
#define NROWS (NBATCH*SEQLEN)   // 16384

typedef __attribute__((ext_vector_type(4))) float  f32x4;
typedef __attribute__((ext_vector_type(8))) __bf16 bf16x8;
typedef __attribute__((ext_vector_type(4))) __bf16 bf16x4;

#define MFMA16(a,b,c) __builtin_amdgcn_mfma_f32_16x16x32_bf16(a,b,c,0,0,0)

// ---------------- workspace layout (bytes) ----------------
static constexpr size_t SZ_ACT_BF16 = (size_t)NROWS * D_MODEL * 2;  // 25165824
static constexpr size_t OFF_H1 = 0;
static constexpr size_t OFF_Q  = OFF_H1 + SZ_ACT_BF16;
static constexpr size_t OFF_K  = OFF_Q  + SZ_ACT_BF16;
static constexpr size_t OFF_V  = OFF_K  + SZ_ACT_BF16;   // Q,K,V contiguous (fused QKV GEMM relies on this)
static constexpr size_t OFF_VT = OFF_V  + SZ_ACT_BF16;
static constexpr size_t OFF_X2 = OFF_VT + SZ_ACT_BF16;              // fp32 buffer
static constexpr size_t OFF_W  = OFF_X2 + (size_t)NROWS * D_MODEL * 4;

__device__ __forceinline__ float gelu_exact(float x) {
  return 0.5f * x * (1.0f + erff(x * 0.70710678118654752f));
}

// ---------------- weight fp32 -> bf16 ----------------
__global__ __launch_bounds__(256) void k_cvt5(
    const float* __restrict__ s0, const float* __restrict__ s1,
    const float* __restrict__ s2, const float* __restrict__ s3,
    const float* __restrict__ s4, __bf16* __restrict__ dst)
{
  const int wsel = blockIdx.y;
  const float* s = wsel==0 ? s0 : wsel==1 ? s1 : wsel==2 ? s2 : wsel==3 ? s3 : s4;
  const size_t i = ((size_t)blockIdx.x*256 + threadIdx.x)*4;
  float4 v = *(const float4*)(s + i);
  bf16x4 o;
  o[0] = (__bf16)v.x; o[1] = (__bf16)v.y; o[2] = (__bf16)v.z; o[3] = (__bf16)v.w;
  *(bf16x4*)(dst + (size_t)wsel*589824 + i) = o;
}

// ---------------- LayerNorm (wave per row) ----------------
__global__ __launch_bounds__(256) void k_layernorm(
    const float* __restrict__ x, const float* __restrict__ g,
    const float* __restrict__ be, __bf16* __restrict__ out)
{
  const int row  = blockIdx.x*4 + (threadIdx.x>>6);
  const int lane = threadIdx.x & 63;
  const float4* xr = (const float4*)(x + (size_t)row*D_MODEL);
  float4 v[3];
  float s = 0.f, ss = 0.f;
#pragma unroll
  for (int j=0;j<3;j++){
    v[j] = xr[lane + 64*j];
    s  += v[j].x + v[j].y + v[j].z + v[j].w;
    ss += v[j].x*v[j].x + v[j].y*v[j].y + v[j].z*v[j].z + v[j].w*v[j].w;
  }
#pragma unroll
  for (int d=1; d<64; d<<=1){ s += __shfl_xor(s,d); ss += __shfl_xor(ss,d); }
  const float mu   = s  * (1.f/768.f);
  const float var  = ss * (1.f/768.f) - mu*mu;
  const float rstd = rsqrtf(var + 1e-5f);
  __bf16* orow = out + (size_t)row*D_MODEL;
#pragma unroll
  for (int j=0;j<3;j++){
    const int c0 = (lane + 64*j)*4;
    bf16x4 o;
    o[0] = (__bf16)((v[j].x - mu)*rstd*g[c0+0] + be[c0+0]);
    o[1] = (__bf16)((v[j].y - mu)*rstd*g[c0+1] + be[c0+1]);
    o[2] = (__bf16)((v[j].z - mu)*rstd*g[c0+2] + be[c0+2]);
    o[3] = (__bf16)((v[j].w - mu)*rstd*g[c0+3] + be[c0+3]);
    *(bf16x4*)(orow + c0) = o;
  }
}

// ---------------- generic NT GEMM body ----------------
// C[M,768] = A[M,768] @ B[768,768]^T + bias ; EPI: 1 = bf16+GELU, 2 = f32+GELU+resid
template<int EPI>
__global__ __launch_bounds__(256) void k_gemm_nt(
    const __bf16* __restrict__ A, const __bf16* __restrict__ B,
    const float* __restrict__ bias, const float* __restrict__ resid,
    void* __restrict__ Cout)
{
  __shared__ __bf16 As[128*64];
  __shared__ __bf16 Bs[128*64];
  const int tid = threadIdx.x;
  const int w = tid>>6, lane = tid&63;
  const int l16 = lane&15, l4 = lane>>4;
  const int bm = blockIdx.x / 6, bn = blockIdx.x % 6;
  const int wr = w>>1, wc = w&1;
  const int srow = lane>>3, schunk = lane&7;
  f32x4 acc[4][4] = {};

  const __bf16* Ab = A + (size_t)bm*128*D_MODEL;
  const __bf16* Bb = B + (size_t)bn*128*D_MODEL;

  for (int k0=0; k0<D_MODEL; k0+=64){
#pragma unroll
    for (int i=0;i<4;i++){
      const int row = i*32 + w*8 + srow;
      __builtin_amdgcn_global_load_lds(
        (const __attribute__((address_space(1))) void*)(Ab + (size_t)row*D_MODEL + k0 + schunk*8),
        (__attribute__((address_space(3))) void*)(As + i*2048 + w*512), 16, 0, 0);
      __builtin_amdgcn_global_load_lds(
        (const __attribute__((address_space(1))) void*)(Bb + (size_t)row*D_MODEL + k0 + schunk*8),
        (__attribute__((address_space(3))) void*)(Bs + i*2048 + w*512), 16, 0, 0);
    }
    __syncthreads();
#pragma unroll
    for (int kk=0;kk<2;kk++){
      bf16x8 af[4], bfr[4];
#pragma unroll
      for (int m=0;m<4;m++)
        af[m] = *(const bf16x8*)(As + (wr*64 + m*16 + l16)*64 + kk*32 + l4*8);
#pragma unroll
      for (int n=0;n<4;n++)
        bfr[n] = *(const bf16x8*)(Bs + (wc*64 + n*16 + l16)*64 + kk*32 + l4*8);
#pragma unroll
      for (int m=0;m<4;m++)
#pragma unroll
        for (int n=0;n<4;n++)
          acc[m][n] = MFMA16(af[m], bfr[n], acc[m][n]);
    }
    __syncthreads();
  }

  const int row0 = bm*128 + wr*64, col0 = bn*128 + wc*64;
#pragma unroll
  for (int n=0;n<4;n++){
    const int col = col0 + n*16 + l16;
    const float bv = bias[col];
#pragma unroll
    for (int m=0;m<4;m++){
#pragma unroll
      for (int r=0;r<4;r++){
        const int row = row0 + m*16 + l4*4 + r;
        float v = acc[m][n][r] + bv;
        if (EPI >= 1) v = gelu_exact(v);
        if (EPI == 2) {
          v += resid[(size_t)row*D_MODEL + col];
          ((float*)Cout)[(size_t)row*D_MODEL + col] = v;
        } else {
          ((__bf16*)Cout)[(size_t)row*D_MODEL + col] = (__bf16)v;
        }
      }
    }
  }
}

// ---------------- fused QKV GEMM: N = 3*768, weights/outs contiguous ----------------
__global__ __launch_bounds__(256) void k_gemm_qkv(
    const __bf16* __restrict__ A, const __bf16* __restrict__ Wcat,
    const float* __restrict__ bq, const float* __restrict__ bk,
    const float* __restrict__ bv, __bf16* __restrict__ out)
{
  __shared__ __bf16 As[128*64];
  __shared__ __bf16 Bs[128*64];
  const int tid = threadIdx.x;
  const int w = tid>>6, lane = tid&63;
  const int l16 = lane&15, l4 = lane>>4;
  const int bm = blockIdx.x / 18, bn = blockIdx.x % 18;
  const int seg = bn/6, bn2 = bn%6;
  const float* bias = seg==0 ? bq : seg==1 ? bk : bv;
  const __bf16* Bb = Wcat + (size_t)seg*589824 + (size_t)bn2*128*D_MODEL;
  __bf16* C = out + (size_t)seg*((size_t)NROWS*D_MODEL);
  const int wr = w>>1, wc = w&1;
  const int srow = lane>>3, schunk = lane&7;
  f32x4 acc[4][4] = {};
  const __bf16* Ab = A + (size_t)bm*128*D_MODEL;

  for (int k0=0; k0<D_MODEL; k0+=64){
#pragma unroll
    for (int i=0;i<4;i++){
      const int row = i*32 + w*8 + srow;
      __builtin_amdgcn_global_load_lds(
        (const __attribute__((address_space(1))) void*)(Ab + (size_t)row*D_MODEL + k0 + schunk*8),
        (__attribute__((address_space(3))) void*)(As + i*2048 + w*512), 16, 0, 0);
      __builtin_amdgcn_global_load_lds(
        (const __attribute__((address_space(1))) void*)(Bb + (size_t)row*D_MODEL + k0 + schunk*8),
        (__attribute__((address_space(3))) void*)(Bs + i*2048 + w*512), 16, 0, 0);
    }
    __syncthreads();
#pragma unroll
    for (int kk=0;kk<2;kk++){
      bf16x8 af[4], bfr[4];
#pragma unroll
      for (int m=0;m<4;m++)
        af[m] = *(const bf16x8*)(As + (wr*64 + m*16 + l16)*64 + kk*32 + l4*8);
#pragma unroll
      for (int n=0;n<4;n++)
        bfr[n] = *(const bf16x8*)(Bs + (wc*64 + n*16 + l16)*64 + kk*32 + l4*8);
#pragma unroll
      for (int m=0;m<4;m++)
#pragma unroll
        for (int n=0;n<4;n++)
          acc[m][n] = MFMA16(af[m], bfr[n], acc[m][n]);
    }
    __syncthreads();
  }

  const int row0 = bm*128 + wr*64, col0 = bn2*128 + wc*64;
#pragma unroll
  for (int n=0;n<4;n++){
    const int col = col0 + n*16 + l16;
    const float bvv = bias[col];
#pragma unroll
    for (int m=0;m<4;m++){
#pragma unroll
      for (int r=0;r<4;r++){
        const int row = row0 + m*16 + l4*4 + r;
        C[(size_t)row*D_MODEL + col] = (__bf16)(acc[m][n][r] + bvv);
      }
    }
  }
}

// ---------------- V transpose: v[b,t,d] -> vT[b,d,t] ----------------
__global__ __launch_bounds__(256) void k_transpose_v(
    const __bf16* __restrict__ v, __bf16* __restrict__ vT)
{
  __shared__ __bf16 tile[64][72];
  const int b = blockIdx.z;
  const int t0 = blockIdx.x*64, d0 = blockIdx.y*64;
  const int tid = threadIdx.x;
  const int rr = (tid>>3)*2, cc = (tid&7)*8;
  const __bf16* src = v + ((size_t)b*SEQLEN + t0)*D_MODEL + d0;
#pragma unroll
  for (int j=0;j<2;j++){
    bf16x8 val = *(const bf16x8*)(src + (size_t)(rr+j)*D_MODEL + cc);
#pragma unroll
    for (int e=0;e<8;e++) tile[cc+e][rr+j] = val[e];
  }
  __syncthreads();
  __bf16* dst = vT + ((size_t)b*D_MODEL + d0)*SEQLEN + t0;
#pragma unroll
  for (int j=0;j<2;j++){
    bf16x8 o;
#pragma unroll
    for (int e=0;e<8;e++) o[e] = tile[rr+j][cc+e];
    *(bf16x8*)(dst + (size_t)(rr+j)*SEQLEN + cc) = o;
  }
}

// ---------------- flash attention v4 + residual ----------------
// Identical structure to v3 (QBLK=32, 8 waves, TBLK=256, full D=768), but
// __launch_bounds__(512,2): empirically this toolchain's 2nd arg acts like
// blocks/CU -> (512,2) yields a 128-VGPR budget (round2 evidence), (512,4)
// yielded 64 and catastrophic scratch spill (round3). Live set ~110 regs.
// LDS 66 KB -> 2 blocks/CU = 16 waves/CU.
#define QBLK 32
#define TBLK 256
__global__ __launch_bounds__(512,2) void k_flash4(
    const __bf16* __restrict__ q, const __bf16* __restrict__ k,
    const __bf16* __restrict__ vT, const float* __restrict__ x,
    float* __restrict__ x2)
{
  __shared__ __bf16 Qs[QBLK*768];       // 48 KB, XOR-swizzled 16B chunks
  __shared__ __bf16 Ps[QBLK*TBLK];      // 16 KB, XOR-swizzled
  __shared__ float pmax[8][QBLK];
  __shared__ float psum[8][QBLK];

  const int tid = threadIdx.x, w = tid>>6, lane = tid&63;
  const int l16 = lane&15, l4 = lane>>4;
  const int b = blockIdx.x & 7, qt = blockIdx.x >> 3;   // batch->XCD affinity
  const __bf16* qg = q  + ((size_t)b*SEQLEN + qt*QBLK)*D_MODEL;
  const __bf16* kg = k  + (size_t)b*SEQLEN*D_MODEL;
  const __bf16* vg = vT + (size_t)b*D_MODEL*SEQLEN;
  const float scale = 0.03608439182435161f;  // 1/sqrt(768)

  // stage Q -> LDS (swizzled): 3072 chunks of 16B, 6 per thread
#pragma unroll
  for (int j=0;j<6;j++){
    const int id = tid + 512*j;
    const int row = id/96, c = id%96;
    bf16x8 v = *(const bf16x8*)(qg + (size_t)row*D_MODEL + c*8);
    *(bf16x8*)(Qs + row*768 + ((c ^ (row&7))*8)) = v;
  }
  __syncthreads();

  f32x4 o[2][6] = {};
  f32x4 m_run[2], l_run[2];
#pragma unroll
  for (int m=0;m<2;m++)
#pragma unroll
    for (int r=0;r<4;r++){ m_run[m][r] = -1e30f; l_run[m][r] = 0.f; }

  for (int t0=0; t0<SEQLEN; t0+=TBLK){
    // ---- QK^T (full 768-deep): S[32][w*32..+32] ----
    f32x4 s[2][2] = {};
    __builtin_amdgcn_s_setprio(1);
#pragma unroll 4
    for (int kk=0; kk<24; kk++){
      const int qswz = ((kk*4 + l4) ^ (l16&7))*8;
      const bf16x8 a0 = *(const bf16x8*)(Qs + (     l16)*768 + qswz);
      const bf16x8 a1 = *(const bf16x8*)(Qs + (16 + l16)*768 + qswz);
      const bf16x8 kf0 = *(const bf16x8*)(kg + (size_t)(t0 + w*32 +      l16)*D_MODEL + kk*32 + l4*8);
      const bf16x8 kf1 = *(const bf16x8*)(kg + (size_t)(t0 + w*32 + 16 + l16)*D_MODEL + kk*32 + l4*8);
      s[0][0] = MFMA16(a0, kf0, s[0][0]);
      s[1][0] = MFMA16(a1, kf0, s[1][0]);
      s[0][1] = MFMA16(a0, kf1, s[0][1]);
      s[1][1] = MFMA16(a1, kf1, s[1][1]);
    }
    __builtin_amdgcn_s_setprio(0);

    // scale + per-wave rowmax over its 32 cols
#pragma unroll
    for (int m=0;m<2;m++)
#pragma unroll
      for (int n=0;n<2;n++)
#pragma unroll
        for (int r=0;r<4;r++) s[m][n][r] *= scale;
#pragma unroll
    for (int m=0;m<2;m++)
#pragma unroll
      for (int r=0;r<4;r++){
        float v = fmaxf(s[m][0][r], s[m][1][r]);
#pragma unroll
        for (int d=1; d<16; d<<=1) v = fmaxf(v, __shfl_xor(v, d));
        if (l16==0) pmax[w][m*16 + l4*4 + r] = v;
      }
    __syncthreads();   // b1: pmax ready

    // ---- m_new (vector form, rows = m*16 + l4*4 + 0..3) ----
    f32x4 mnew[2];
#pragma unroll
    for (int m=0;m<2;m++){
      f32x4 mv = *(const f32x4*)&pmax[0][m*16 + l4*4];
#pragma unroll
      for (int ww=1; ww<8; ww++){
        const f32x4 t = *(const f32x4*)&pmax[ww][m*16 + l4*4];
#pragma unroll
        for (int r=0;r<4;r++) mv[r] = fmaxf(mv[r], t[r]);
      }
#pragma unroll
      for (int r=0;r<4;r++) mnew[m][r] = fmaxf(m_run[m][r], mv[r]);
    }

    // ---- exp, partial row-sums, write P (bf16, swizzled) ----
#pragma unroll
    for (int m=0;m<2;m++)
#pragma unroll
      for (int r=0;r<4;r++){
        const float mn = mnew[m][r];
        float sum = 0.f;
#pragma unroll
        for (int n=0;n<2;n++){
          const float e = __expf(s[m][n][r] - mn);
          s[m][n][r] = e; sum += e;
        }
#pragma unroll
        for (int d=1; d<16; d<<=1) sum += __shfl_xor(sum, d);
        const int row = m*16 + l4*4 + r;
        if (l16==0) psum[w][row] = sum;
#pragma unroll
        for (int n=0;n<2;n++){
          const int col = w*32 + n*16 + l16;
          Ps[row*TBLK + (((col>>3) ^ (row&7))<<3) + (col&7)] = (__bf16)s[m][n][r];
        }
      }
    __syncthreads();   // b2: P + psum ready

    // ---- alpha, l_run, rescale O ----
#pragma unroll
    for (int m=0;m<2;m++){
      f32x4 sm = *(const f32x4*)&psum[0][m*16 + l4*4];
#pragma unroll
      for (int ww=1; ww<8; ww++){
        const f32x4 t = *(const f32x4*)&psum[ww][m*16 + l4*4];
#pragma unroll
        for (int r=0;r<4;r++) sm[r] += t[r];
      }
      f32x4 al;
#pragma unroll
      for (int r=0;r<4;r++){
        al[r] = __expf(m_run[m][r] - mnew[m][r]);
        l_run[m][r] = l_run[m][r]*al[r] + sm[r];
        m_run[m][r] = mnew[m][r];
      }
#pragma unroll
      for (int n=0;n<6;n++) o[m][n] *= al;
    }

    // ---- PV: O[32 x 96cols] += P[32 x 256] @ V' ----
    __builtin_amdgcn_s_setprio(1);
#pragma unroll 2
    for (int ks=0; ks<8; ks++){
      const bf16x8 pf0 = *(const bf16x8*)(Ps + (     l16)*TBLK + (((ks*4 + l4) ^ (l16&7))<<3));
      const bf16x8 pf1 = *(const bf16x8*)(Ps + (16 + l16)*TBLK + (((ks*4 + l4) ^ (l16&7))<<3));
#pragma unroll
      for (int n=0;n<6;n++){
        const bf16x8 vf = *(const bf16x8*)(vg + (size_t)(w*96 + n*16 + l16)*SEQLEN + t0 + ks*32 + l4*8);
        o[0][n] = MFMA16(pf0, vf, o[0][n]);
        o[1][n] = MFMA16(pf1, vf, o[1][n]);
      }
    }
    __builtin_amdgcn_s_setprio(0);
    __syncthreads();   // b3: Ps/pmax/psum consumed
  }

  // ---- epilogue: /l, + residual, store fp32 ----
  const float* xr = x  + ((size_t)b*SEQLEN + qt*QBLK)*D_MODEL;
  float*       ob = x2 + ((size_t)b*SEQLEN + qt*QBLK)*D_MODEL;
#pragma unroll
  for (int m=0;m<2;m++){
    f32x4 inv;
#pragma unroll
    for (int r=0;r<4;r++) inv[r] = 1.f / l_run[m][r];
#pragma unroll
    for (int r=0;r<4;r++){
      const int row = m*16 + l4*4 + r;
#pragma unroll
      for (int n=0;n<6;n++){
        const int col = w*96 + n*16 + l16;
        ob[(size_t)row*D_MODEL + col] = o[m][n][r]*inv[r] + xr[(size_t)row*D_MODEL + col];
      }
    }
  }
}

// ---------------- launch ----------------
extern "C" void kernel_launch(void* const* d_in, const int* in_sizes, int n_in,
                              void* d_out, int out_size, void* d_ws, size_t ws_size,
                              hipStream_t stream)
{
  const float* x   = (const float*)d_in[0];
  const float* Wq  = (const float*)d_in[1];
  const float* bq  = (const float*)d_in[2];
  const float* Wk  = (const float*)d_in[3];
  const float* bk  = (const float*)d_in[4];
  const float* Wv  = (const float*)d_in[5];
  const float* bv  = (const float*)d_in[6];
  const float* W1  = (const float*)d_in[7];
  const float* b1  = (const float*)d_in[8];
  const float* W2  = (const float*)d_in[9];
  const float* b2  = (const float*)d_in[10];
  const float* g1  = (const float*)d_in[11];
  const float* be1 = (const float*)d_in[12];
  const float* g2  = (const float*)d_in[13];
  const float* be2 = (const float*)d_in[14];
  (void)in_sizes; (void)n_in; (void)out_size; (void)ws_size;

  char* ws = (char*)d_ws;
  __bf16* h1  = (__bf16*)(ws + OFF_H1);
  __bf16* qb  = (__bf16*)(ws + OFF_Q);
  __bf16* vb  = (__bf16*)(ws + OFF_V);
  __bf16* vT  = (__bf16*)(ws + OFF_VT);
  float*  x2  = (float*)(ws + OFF_X2);
  __bf16* wbf = (__bf16*)(ws + OFF_W);
  __bf16* kb  = (__bf16*)(ws + OFF_K);
  __bf16* h2  = h1;   // reuse (h1 dead after QKV GEMM)
  __bf16* h3  = qb;   // reuse (q dead after attention)

  k_cvt5<<<dim3(576,5,1),256,0,stream>>>(Wq,Wk,Wv,W1,W2,wbf);
  k_layernorm<<<dim3(4096),256,0,stream>>>(x, g1, be1, h1);
  k_gemm_qkv<<<dim3(2304),256,0,stream>>>(h1, wbf, bq, bk, bv, qb);
  k_transpose_v<<<dim3(32,12,8),256,0,stream>>>(vb, vT);
  k_flash4<<<dim3(512),512,0,stream>>>(qb, kb, vT, x, x2);
  k_layernorm<<<dim3(4096),256,0,stream>>>(x2, g2, be2, h2);
  k_gemm_nt<1><<<dim3(768),256,0,stream>>>(h2, wbf + 3*589824, b1, nullptr, h3);
  k_gemm_nt<2><<<dim3(768),256,0,stream>>>(h3, wbf + 4*589824, b2, x2, d_out);
}

// Round 5
// 501.083 us; speedup vs baseline: 1.6812x; 1.3640x over previous
//
#include <hip/hip_runtime.h>
#include <cstdint>
#include <cstddef>

#define D_MODEL 768
#define NBATCH 8
#define SEQLEN 2048
#define NROWS (NBATCH*SEQLEN)   // 16384

typedef __attribute__((ext_vector_type(4))) float  f32x4;
typedef __attribute__((ext_vector_type(8))) __bf16 bf16x8;
typedef __attribute__((ext_vector_type(4))) __bf16 bf16x4;
typedef __attribute__((ext_vector_type(8))) _Float16 f16x8;

#define MFMA16(a,b,c) __builtin_amdgcn_mfma_f32_16x16x32_bf16(a,b,c,0,0,0)
#define SCALE 0.03608439182435161f   // 1/sqrt(768)

// ---------------- workspace layout (bytes) ----------------
// Q | K | VT | X2 | W | POOL
// POOL holds, over time: {h1, v} -> {S chunk (4 batches fp16)} -> {h2}
static constexpr size_t SZ_ACT = (size_t)NROWS * D_MODEL * 2;       // 25165824
static constexpr size_t OFF_Q    = 0;
static constexpr size_t OFF_K    = OFF_Q + SZ_ACT;
static constexpr size_t OFF_VT   = OFF_K + SZ_ACT;
static constexpr size_t OFF_X2   = OFF_VT + SZ_ACT;                 // fp32
static constexpr size_t OFF_W    = OFF_X2 + (size_t)NROWS*D_MODEL*4;
static constexpr size_t OFF_POOL = OFF_W + 5*589824*2;
// POOL usage: h1 @ +0 (25.2MB), v @ +SZ_ACT (25.2MB); S chunk @ +0 (33.6MB)
// total = 131727360 + 50331648 = ~182 MB (same footprint as prior rounds)

__device__ __forceinline__ float gelu_exact(float x) {
  return 0.5f * x * (1.0f + erff(x * 0.70710678118654752f));
}

// ---------------- weight fp32 -> bf16 ----------------
__global__ __launch_bounds__(256) void k_cvt5(
    const float* __restrict__ s0, const float* __restrict__ s1,
    const float* __restrict__ s2, const float* __restrict__ s3,
    const float* __restrict__ s4, __bf16* __restrict__ dst)
{
  const int wsel = blockIdx.y;
  const float* s = wsel==0 ? s0 : wsel==1 ? s1 : wsel==2 ? s2 : wsel==3 ? s3 : s4;
  const size_t i = ((size_t)blockIdx.x*256 + threadIdx.x)*4;
  float4 v = *(const float4*)(s + i);
  bf16x4 o;
  o[0] = (__bf16)v.x; o[1] = (__bf16)v.y; o[2] = (__bf16)v.z; o[3] = (__bf16)v.w;
  *(bf16x4*)(dst + (size_t)wsel*589824 + i) = o;
}

// ---------------- LayerNorm (wave per row) ----------------
__global__ __launch_bounds__(256) void k_layernorm(
    const float* __restrict__ x, const float* __restrict__ g,
    const float* __restrict__ be, __bf16* __restrict__ out)
{
  const int row  = blockIdx.x*4 + (threadIdx.x>>6);
  const int lane = threadIdx.x & 63;
  const float4* xr = (const float4*)(x + (size_t)row*D_MODEL);
  float4 v[3];
  float s = 0.f, ss = 0.f;
#pragma unroll
  for (int j=0;j<3;j++){
    v[j] = xr[lane + 64*j];
    s  += v[j].x + v[j].y + v[j].z + v[j].w;
    ss += v[j].x*v[j].x + v[j].y*v[j].y + v[j].z*v[j].z + v[j].w*v[j].w;
  }
#pragma unroll
  for (int d=1; d<64; d<<=1){ s += __shfl_xor(s,d); ss += __shfl_xor(ss,d); }
  const float mu   = s  * (1.f/768.f);
  const float var  = ss * (1.f/768.f) - mu*mu;
  const float rstd = rsqrtf(var + 1e-5f);
  __bf16* orow = out + (size_t)row*D_MODEL;
#pragma unroll
  for (int j=0;j<3;j++){
    const int c0 = (lane + 64*j)*4;
    bf16x4 o;
    o[0] = (__bf16)((v[j].x - mu)*rstd*g[c0+0] + be[c0+0]);
    o[1] = (__bf16)((v[j].y - mu)*rstd*g[c0+1] + be[c0+1]);
    o[2] = (__bf16)((v[j].z - mu)*rstd*g[c0+2] + be[c0+2]);
    o[3] = (__bf16)((v[j].w - mu)*rstd*g[c0+3] + be[c0+3]);
    *(bf16x4*)(orow + c0) = o;
  }
}

// ---------------- generic 768-K NT GEMM (MLP) ----------------
// C[M,768] = A[M,768] @ B[768,768]^T + bias ; EPI: 1 = bf16+GELU, 2 = f32+GELU+resid
template<int EPI>
__global__ __launch_bounds__(256) void k_gemm_nt(
    const __bf16* __restrict__ A, const __bf16* __restrict__ B,
    const float* __restrict__ bias, const float* __restrict__ resid,
    void* __restrict__ Cout)
{
  __shared__ __bf16 As[128*64];
  __shared__ __bf16 Bs[128*64];
  const int tid = threadIdx.x;
  const int w = tid>>6, lane = tid&63;
  const int l16 = lane&15, l4 = lane>>4;
  const int bm = blockIdx.x / 6, bn = blockIdx.x % 6;
  const int wr = w>>1, wc = w&1;
  const int srow = lane>>3, schunk = lane&7;
  f32x4 acc[4][4] = {};

  const __bf16* Ab = A + (size_t)bm*128*D_MODEL;
  const __bf16* Bb = B + (size_t)bn*128*D_MODEL;

  for (int k0=0; k0<D_MODEL; k0+=64){
#pragma unroll
    for (int i=0;i<4;i++){
      const int row = i*32 + w*8 + srow;
      __builtin_amdgcn_global_load_lds(
        (const __attribute__((address_space(1))) void*)(Ab + (size_t)row*D_MODEL + k0 + schunk*8),
        (__attribute__((address_space(3))) void*)(As + i*2048 + w*512), 16, 0, 0);
      __builtin_amdgcn_global_load_lds(
        (const __attribute__((address_space(1))) void*)(Bb + (size_t)row*D_MODEL + k0 + schunk*8),
        (__attribute__((address_space(3))) void*)(Bs + i*2048 + w*512), 16, 0, 0);
    }
    __syncthreads();
#pragma unroll
    for (int kk=0;kk<2;kk++){
      bf16x8 af[4], bfr[4];
#pragma unroll
      for (int m=0;m<4;m++)
        af[m] = *(const bf16x8*)(As + (wr*64 + m*16 + l16)*64 + kk*32 + l4*8);
#pragma unroll
      for (int n=0;n<4;n++)
        bfr[n] = *(const bf16x8*)(Bs + (wc*64 + n*16 + l16)*64 + kk*32 + l4*8);
#pragma unroll
      for (int m=0;m<4;m++)
#pragma unroll
        for (int n=0;n<4;n++)
          acc[m][n] = MFMA16(af[m], bfr[n], acc[m][n]);
    }
    __syncthreads();
  }

  const int row0 = bm*128 + wr*64, col0 = bn*128 + wc*64;
#pragma unroll
  for (int n=0;n<4;n++){
    const int col = col0 + n*16 + l16;
    const float bv = bias[col];
#pragma unroll
    for (int m=0;m<4;m++){
#pragma unroll
      for (int r=0;r<4;r++){
        const int row = row0 + m*16 + l4*4 + r;
        float v = acc[m][n][r] + bv;
        if (EPI >= 1) v = gelu_exact(v);
        if (EPI == 2) {
          v += resid[(size_t)row*D_MODEL + col];
          ((float*)Cout)[(size_t)row*D_MODEL + col] = v;
        } else {
          ((__bf16*)Cout)[(size_t)row*D_MODEL + col] = (__bf16)v;
        }
      }
    }
  }
}

// ---------------- fused QKV GEMM (Q pre-scaled by 1/sqrt(768)) ----------------
__global__ __launch_bounds__(256) void k_gemm_qkv(
    const __bf16* __restrict__ A, const __bf16* __restrict__ Wcat,
    const float* __restrict__ bq, const float* __restrict__ bk,
    const float* __restrict__ bv,
    __bf16* __restrict__ Cq, __bf16* __restrict__ Ck, __bf16* __restrict__ Cv)
{
  __shared__ __bf16 As[128*64];
  __shared__ __bf16 Bs[128*64];
  const int tid = threadIdx.x;
  const int w = tid>>6, lane = tid&63;
  const int l16 = lane&15, l4 = lane>>4;
  const int bm = blockIdx.x / 18, bn = blockIdx.x % 18;
  const int seg = bn/6, bn2 = bn%6;
  const float* bias = seg==0 ? bq : seg==1 ? bk : bv;
  const __bf16* Bb = Wcat + (size_t)seg*589824 + (size_t)bn2*128*D_MODEL;
  __bf16* C = seg==0 ? Cq : seg==1 ? Ck : Cv;
  const int wr = w>>1, wc = w&1;
  const int srow = lane>>3, schunk = lane&7;
  f32x4 acc[4][4] = {};
  const __bf16* Ab = A + (size_t)bm*128*D_MODEL;

  for (int k0=0; k0<D_MODEL; k0+=64){
#pragma unroll
    for (int i=0;i<4;i++){
      const int row = i*32 + w*8 + srow;
      __builtin_amdgcn_global_load_lds(
        (const __attribute__((address_space(1))) void*)(Ab + (size_t)row*D_MODEL + k0 + schunk*8),
        (__attribute__((address_space(3))) void*)(As + i*2048 + w*512), 16, 0, 0);
      __builtin_amdgcn_global_load_lds(
        (const __attribute__((address_space(1))) void*)(Bb + (size_t)row*D_MODEL + k0 + schunk*8),
        (__attribute__((address_space(3))) void*)(Bs + i*2048 + w*512), 16, 0, 0);
    }
    __syncthreads();
#pragma unroll
    for (int kk=0;kk<2;kk++){
      bf16x8 af[4], bfr[4];
#pragma unroll
      for (int m=0;m<4;m++)
        af[m] = *(const bf16x8*)(As + (wr*64 + m*16 + l16)*64 + kk*32 + l4*8);
#pragma unroll
      for (int n=0;n<4;n++)
        bfr[n] = *(const bf16x8*)(Bs + (wc*64 + n*16 + l16)*64 + kk*32 + l4*8);
#pragma unroll
      for (int m=0;m<4;m++)
#pragma unroll
        for (int n=0;n<4;n++)
          acc[m][n] = MFMA16(af[m], bfr[n], acc[m][n]);
    }
    __syncthreads();
  }

  const int row0 = bm*128 + wr*64, col0 = bn2*128 + wc*64;
#pragma unroll
  for (int n=0;n<4;n++){
    const int col = col0 + n*16 + l16;
    const float bvv = bias[col];
#pragma unroll
    for (int m=0;m<4;m++){
#pragma unroll
      for (int r=0;r<4;r++){
        const int row = row0 + m*16 + l4*4 + r;
        float v = acc[m][n][r] + bvv;
        if (seg==0) v *= SCALE;
        C[(size_t)row*D_MODEL + col] = (__bf16)v;
      }
    }
  }
}

// ---------------- V transpose: v[b,t,d] -> vT[b,d,t] ----------------
__global__ __launch_bounds__(256) void k_transpose_v(
    const __bf16* __restrict__ v, __bf16* __restrict__ vT)
{
  __shared__ __bf16 tile[64][72];
  const int b = blockIdx.z;
  const int t0 = blockIdx.x*64, d0 = blockIdx.y*64;
  const int tid = threadIdx.x;
  const int rr = (tid>>3)*2, cc = (tid&7)*8;
  const __bf16* src = v + ((size_t)b*SEQLEN + t0)*D_MODEL + d0;
#pragma unroll
  for (int j=0;j<2;j++){
    bf16x8 val = *(const bf16x8*)(src + (size_t)(rr+j)*D_MODEL + cc);
#pragma unroll
    for (int e=0;e<8;e++) tile[cc+e][rr+j] = val[e];
  }
  __syncthreads();
  __bf16* dst = vT + ((size_t)b*D_MODEL + d0)*SEQLEN + t0;
#pragma unroll
  for (int j=0;j<2;j++){
    bf16x8 o;
#pragma unroll
    for (int e=0;e<8;e++) o[e] = tile[rr+j][cc+e];
    *(bf16x8*)(dst + (size_t)(rr+j)*SEQLEN + cc) = o;
  }
}

// ---------------- S = Qs @ K^T (per local batch), fp16 out ----------------
// grid (256, nb): x -> 16x16 tiles of 128, y -> local batch
__global__ __launch_bounds__(256) void k_gemm_s(
    const __bf16* __restrict__ Qc, const __bf16* __restrict__ Kc,
    _Float16* __restrict__ S)
{
  __shared__ __bf16 As[128*64];
  __shared__ __bf16 Bs[128*64];
  const int tid = threadIdx.x;
  const int w = tid>>6, lane = tid&63;
  const int l16 = lane&15, l4 = lane>>4;
  const int bm = blockIdx.x >> 4, bn = blockIdx.x & 15;
  const size_t boff = (size_t)blockIdx.y * SEQLEN * D_MODEL;
  const __bf16* Ab = Qc + boff + (size_t)bm*128*D_MODEL;
  const __bf16* Bb = Kc + boff + (size_t)bn*128*D_MODEL;
  _Float16* Cb = S + (size_t)blockIdx.y*SEQLEN*SEQLEN;
  const int wr = w>>1, wc = w&1;
  const int srow = lane>>3, schunk = lane&7;
  f32x4 acc[4][4] = {};

  for (int k0=0; k0<D_MODEL; k0+=64){
#pragma unroll
    for (int i=0;i<4;i++){
      const int row = i*32 + w*8 + srow;
      __builtin_amdgcn_global_load_lds(
        (const __attribute__((address_space(1))) void*)(Ab + (size_t)row*D_MODEL + k0 + schunk*8),
        (__attribute__((address_space(3))) void*)(As + i*2048 + w*512), 16, 0, 0);
      __builtin_amdgcn_global_load_lds(
        (const __attribute__((address_space(1))) void*)(Bb + (size_t)row*D_MODEL + k0 + schunk*8),
        (__attribute__((address_space(3))) void*)(Bs + i*2048 + w*512), 16, 0, 0);
    }
    __syncthreads();
#pragma unroll
    for (int kk=0;kk<2;kk++){
      bf16x8 af[4], bfr[4];
#pragma unroll
      for (int m=0;m<4;m++)
        af[m] = *(const bf16x8*)(As + (wr*64 + m*16 + l16)*64 + kk*32 + l4*8);
#pragma unroll
      for (int n=0;n<4;n++)
        bfr[n] = *(const bf16x8*)(Bs + (wc*64 + n*16 + l16)*64 + kk*32 + l4*8);
#pragma unroll
      for (int m=0;m<4;m++)
#pragma unroll
        for (int n=0;n<4;n++)
          acc[m][n] = MFMA16(af[m], bfr[n], acc[m][n]);
    }
    __syncthreads();
  }

  const int row0 = bm*128 + wr*64, col0 = bn*128 + wc*64;
#pragma unroll
  for (int n=0;n<4;n++){
    const int col = col0 + n*16 + l16;
#pragma unroll
    for (int m=0;m<4;m++){
#pragma unroll
      for (int r=0;r<4;r++){
        const int row = row0 + m*16 + l4*4 + r;
        Cb[(size_t)row*SEQLEN + col] = (_Float16)acc[m][n][r];
      }
    }
  }
}

// ---------------- row softmax, in-place fp16 -> bf16 ----------------
__global__ __launch_bounds__(256) void k_softmax(_Float16* __restrict__ S)
{
  const int row  = blockIdx.x*4 + (threadIdx.x>>6);
  const int lane = threadIdx.x & 63;
  _Float16* sr = S + (size_t)row*SEQLEN + lane*32;
  f16x8 v[4];
#pragma unroll
  for (int j=0;j<4;j++) v[j] = *(const f16x8*)(sr + j*8);
  float f[32];
  float mx = -1e30f;
#pragma unroll
  for (int j=0;j<4;j++)
#pragma unroll
    for (int e=0;e<8;e++){ f[j*8+e] = (float)v[j][e]; mx = fmaxf(mx, f[j*8+e]); }
#pragma unroll
  for (int d=1; d<64; d<<=1) mx = fmaxf(mx, __shfl_xor(mx, d));
  float sum = 0.f;
#pragma unroll
  for (int i=0;i<32;i++){ f[i] = __expf(f[i]-mx); sum += f[i]; }
#pragma unroll
  for (int d=1; d<64; d<<=1) sum += __shfl_xor(sum, d);
  const float inv = 1.f/sum;
  __bf16* pr = (__bf16*)(S + (size_t)row*SEQLEN) + lane*32;
#pragma unroll
  for (int j=0;j<4;j++){
    bf16x8 o;
#pragma unroll
    for (int e=0;e<8;e++) o[e] = (__bf16)(f[j*8+e]*inv);
    *(bf16x8*)(pr + j*8) = o;
  }
}

// ---------------- O = P @ V + x (per local batch), fp32 out ----------------
// grid (96, nb): x -> 16x6 tiles of 128, y -> local batch; bbase = chunk*4
__global__ __launch_bounds__(256) void k_gemm_pv(
    const __bf16* __restrict__ P, const __bf16* __restrict__ vT,
    const float* __restrict__ x, float* __restrict__ x2, int bbase)
{
  __shared__ __bf16 As[128*64];
  __shared__ __bf16 Bs[128*64];
  const int tid = threadIdx.x;
  const int w = tid>>6, lane = tid&63;
  const int l16 = lane&15, l4 = lane>>4;
  const int bm = blockIdx.x / 6, bn = blockIdx.x % 6;
  const int b_act = bbase + blockIdx.y;
  const __bf16* Ab = P  + (size_t)blockIdx.y*SEQLEN*SEQLEN + (size_t)bm*128*SEQLEN;
  const __bf16* Bb = vT + (size_t)b_act*D_MODEL*SEQLEN + (size_t)bn*128*SEQLEN;
  const int wr = w>>1, wc = w&1;
  const int srow = lane>>3, schunk = lane&7;
  f32x4 acc[4][4] = {};

  for (int k0=0; k0<SEQLEN; k0+=64){
#pragma unroll
    for (int i=0;i<4;i++){
      const int row = i*32 + w*8 + srow;
      __builtin_amdgcn_global_load_lds(
        (const __attribute__((address_space(1))) void*)(Ab + (size_t)row*SEQLEN + k0 + schunk*8),
        (__attribute__((address_space(3))) void*)(As + i*2048 + w*512), 16, 0, 0);
      __builtin_amdgcn_global_load_lds(
        (const __attribute__((address_space(1))) void*)(Bb + (size_t)row*SEQLEN + k0 + schunk*8),
        (__attribute__((address_space(3))) void*)(Bs + i*2048 + w*512), 16, 0, 0);
    }
    __syncthreads();
#pragma unroll
    for (int kk=0;kk<2;kk++){
      bf16x8 af[4], bfr[4];
#pragma unroll
      for (int m=0;m<4;m++)
        af[m] = *(const bf16x8*)(As + (wr*64 + m*16 + l16)*64 + kk*32 + l4*8);
#pragma unroll
      for (int n=0;n<4;n++)
        bfr[n] = *(const bf16x8*)(Bs + (wc*64 + n*16 + l16)*64 + kk*32 + l4*8);
#pragma unroll
      for (int m=0;m<4;m++)
#pragma unroll
        for (int n=0;n<4;n++)
          acc[m][n] = MFMA16(af[m], bfr[n], acc[m][n]);
    }
    __syncthreads();
  }

  const size_t rowg0 = (size_t)b_act*SEQLEN + bm*128 + wr*64;
  const int col0 = bn*128 + wc*64;
#pragma unroll
  for (int n=0;n<4;n++){
    const int col = col0 + n*16 + l16;
#pragma unroll
    for (int m=0;m<4;m++){
#pragma unroll
      for (int r=0;r<4;r++){
        const size_t rowg = rowg0 + m*16 + l4*4 + r;
        x2[rowg*D_MODEL + col] = acc[m][n][r] + x[rowg*D_MODEL + col];
      }
    }
  }
}

// ---------------- launch ----------------
extern "C" void kernel_launch(void* const* d_in, const int* in_sizes, int n_in,
                              void* d_out, int out_size, void* d_ws, size_t ws_size,
                              hipStream_t stream)
{
  const float* x   = (const float*)d_in[0];
  const float* Wq  = (const float*)d_in[1];
  const float* bq  = (const float*)d_in[2];
  const float* Wk  = (const float*)d_in[3];
  const float* bk  = (const float*)d_in[4];
  const float* Wv  = (const float*)d_in[5];
  const float* bv  = (const float*)d_in[6];
  const float* W1  = (const float*)d_in[7];
  const float* b1  = (const float*)d_in[8];
  const float* W2  = (const float*)d_in[9];
  const float* b2  = (const float*)d_in[10];
  const float* g1  = (const float*)d_in[11];
  const float* be1 = (const float*)d_in[12];
  const float* g2  = (const float*)d_in[13];
  const float* be2 = (const float*)d_in[14];
  (void)in_sizes; (void)n_in; (void)out_size; (void)ws_size;

  char* ws = (char*)d_ws;
  __bf16*   qb  = (__bf16*)(ws + OFF_Q);
  __bf16*   kb  = (__bf16*)(ws + OFF_K);
  __bf16*   vT  = (__bf16*)(ws + OFF_VT);
  float*    x2  = (float*)(ws + OFF_X2);
  __bf16*   wbf = (__bf16*)(ws + OFF_W);
  __bf16*   h1  = (__bf16*)(ws + OFF_POOL);            // pool slot 0
  __bf16*   vb  = (__bf16*)(ws + OFF_POOL + SZ_ACT);   // pool slot 1
  _Float16* Sp  = (_Float16*)(ws + OFF_POOL);          // S chunk (4 batches) aliases h1+v
  __bf16*   h2  = h1;   // pool reused after attention
  __bf16*   h3  = qb;   // Q dead after attention

  k_cvt5<<<dim3(576,5,1),256,0,stream>>>(Wq,Wk,Wv,W1,W2,wbf);
  k_layernorm<<<dim3(4096),256,0,stream>>>(x, g1, be1, h1);
  k_gemm_qkv<<<dim3(2304),256,0,stream>>>(h1, wbf, bq, bk, bv, qb, kb, vb);
  k_transpose_v<<<dim3(32,12,8),256,0,stream>>>(vb, vT);

  for (int c=0;c<2;c++){
    const size_t qoff = (size_t)c*4*SEQLEN*D_MODEL;
    k_gemm_s <<<dim3(256,4),256,0,stream>>>(qb + qoff, kb + qoff, Sp);
    k_softmax<<<dim3(2048),256,0,stream>>>(Sp);
    k_gemm_pv<<<dim3(96,4),256,0,stream>>>((const __bf16*)Sp, vT, x, x2, c*4);
  }

  k_layernorm<<<dim3(4096),256,0,stream>>>(x2, g2, be2, h2);
  k_gemm_nt<1><<<dim3(768),256,0,stream>>>(h2, wbf + 3*589824, b1, nullptr, h3);
  k_gemm_nt<2><<<dim3(768),256,0,stream>>>(h3, wbf + 4*589824, b2, x2, d_out);
}